// Round 8
// baseline (242.546 us; speedup 1.0000x reference)
//
#include <hip/hip_runtime.h>
#include <math.h>

#define F_NUM 8
#define N_AT 2048
#define E_EDGE 32768
#define FE (F_NUM*E_EDGE)   // 262144 base edges
#define FN (F_NUM*N_AT)     // 16384 atoms
#define CAP 72              // per-atom incidence capacity (avg 32, Poisson)
#define PI_F 3.14159265358979f

__device__ __forceinline__ unsigned short f2b(float x) {
    unsigned int u = __float_as_uint(x);
    u += 0x8000u;
    return (unsigned short)(u >> 16);
}
__device__ __forceinline__ float blo(unsigned int u) { return __uint_as_float(u << 16); }
__device__ __forceinline__ float bhi(unsigned int u) { return __uint_as_float(u & 0xffff0000u); }
__device__ __forceinline__ float b2f(unsigned short u) { return __uint_as_float((unsigned)u << 16); }

// dot of 8 bf16-packed values (uint4) with 8 f32 weights
__device__ __forceinline__ float dot8q(uint4 q, const float* w) {
    return blo(q.x)*w[0] + bhi(q.x)*w[1] + blo(q.y)*w[2] + bhi(q.y)*w[3]
         + blo(q.z)*w[4] + bhi(q.z)*w[5] + blo(q.w)*w[6] + bhi(q.w)*w[7];
}

// ---------------- edges: geometry, bf16 dbasis (edge order), bf16 basis + nb|type (incidence order) ----------------
__global__ __launch_bounds__(256) void k_edges(
    const float* __restrict__ pos, const int* __restrict__ eidx,
    const float* __restrict__ cell, const int* __restrict__ co_p,
    const int* __restrict__ at,
    uint4* __restrict__ dbq, float4* __restrict__ unit,
    int* __restrict__ cnt, int* __restrict__ nbq, uint4* __restrict__ binc)
{
    int k = blockIdx.x * 256 + threadIdx.x;
    if (k >= FE) return;
    int f = k >> 15;
    int e = k & (E_EDGE - 1);
    int a = eidx[f * 2 * E_EDGE + e] + f * N_AT;
    int b = eidx[f * 2 * E_EDGE + E_EDGE + e] + f * N_AT;
    int ta = at[a], tb = at[b];
    float co = (float)co_p[0];

    float vec[3];
#pragma unroll
    for (int d = 0; d < 3; d++) {
        float v  = pos[3 * b + d] - pos[3 * a + d];
        float cl = cell[3 * f + d];
        float sh = cl * ((v < -co ? 1.f : 0.f) - (v > co ? 1.f : 0.f));
        vec[d] = v + sh;
    }
    float r2   = vec[0]*vec[0] + vec[1]*vec[1] + vec[2]*vec[2] + 1e-12f;
    float r    = sqrtf(r2);
    float rinv = 1.f / r;
    unit[k] = make_float4(vec[0]*rinv, vec[1]*rinv, vec[2]*rinv, 0.f);

    float x = r * (1.f / 6.f);           // R_MAX = 6
    float env = 0.f, denv = 0.f;
    if (x < 1.f) {
        float x2 = x*x, x3 = x2*x, x5 = x2*x3, x6 = x5*x, x7 = x6*x, x8 = x7*x;
        env  = 1.f - 28.f*x6 + 48.f*x7 - 21.f*x8;
        denv = -168.f*x5 + 336.f*x6 - 168.f*x7;
    }
    float s1, c1;
    sincosf(PI_F * x, &s1, &c1);
    float sn = s1, cn = c1;
    const float C0 = 0.57735026919f;     // sqrt(2/6)
    float bs[8], db[8];
#pragma unroll
    for (int n = 1; n <= 8; n++) {
        float kn  = (float)n * PI_F * (1.f / 6.f);
        float bes = C0 * sn * rinv;
        bs[n-1] = bes * env;
        db[n-1] = C0 * rinv * (kn * cn - sn * rinv) * env + bes * denv * (1.f / 6.f);
        float sn2 = sn * c1 + cn * s1;
        float cn2 = cn * c1 - sn * s1;
        sn = sn2; cn = cn2;
    }
    uint4 B, D;
    B.x = (unsigned)f2b(bs[0]) | ((unsigned)f2b(bs[1]) << 16);
    B.y = (unsigned)f2b(bs[2]) | ((unsigned)f2b(bs[3]) << 16);
    B.z = (unsigned)f2b(bs[4]) | ((unsigned)f2b(bs[5]) << 16);
    B.w = (unsigned)f2b(bs[6]) | ((unsigned)f2b(bs[7]) << 16);
    D.x = (unsigned)f2b(db[0]) | ((unsigned)f2b(db[1]) << 16);
    D.y = (unsigned)f2b(db[2]) | ((unsigned)f2b(db[3]) << 16);
    D.z = (unsigned)f2b(db[4]) | ((unsigned)f2b(db[5]) << 16);
    D.w = (unsigned)f2b(db[6]) | ((unsigned)f2b(db[7]) << 16);
    dbq[k] = D;

    int sa = atomicAdd(&cnt[a], 1);
    if (sa < CAP) { nbq[a * CAP + sa] = (b << 2) | tb; binc[a * CAP + sa] = B; }
    int sb = atomicAdd(&cnt[b], 1);
    if (sb < CAP) { nbq[b * CAP + sb] = (a << 2) | ta; binc[b * CAP + sb] = B; }
}

// ---------------- g2[c] = sum_d w_out[d] * Wmix2[c,d] ----------------
__global__ void k_g2(const float* __restrict__ w_out, const float* __restrict__ Wmix2, float* __restrict__ g2)
{
    int c = threadIdx.x;
    float acc = 0.f;
#pragma unroll
    for (int d = 0; d < 32; d++) acc += w_out[d] * Wmix2[c * 32 + d];
    g2[c] = acc;
}

// ---------------- forward layer: 2 atoms/block, 4 groups/atom (serial depth ~8) ----------------
template<bool L0>
__global__ __launch_bounds__(256, 8) void k_L(
    const unsigned short* __restrict__ slq, const float* __restrict__ W_embed,
    unsigned short* __restrict__ soq,
    const int* __restrict__ cnt, const int* __restrict__ nbq, const uint4* __restrict__ binc,
    const float* __restrict__ Wrad_l, const float* __restrict__ Wmix_l,
    const int* __restrict__ at)
{
    __shared__ float wmix[1024];
    __shared__ float Ash[2][4][32];
    __shared__ float We[128];
    int t = threadIdx.x;
    for (int i = t; i < 1024; i += 256) wmix[i] = Wmix_l[i];
    if (L0 && t < 128) We[t] = W_embed[t];
    int g = t >> 5, c = t & 31;
    int al = g >> 2, q = g & 3;
    int n = blockIdx.x * 2 + al;
    float wr[8];
#pragma unroll
    for (int bb = 0; bb < 8; bb++) wr[bb] = Wrad_l[bb * 128 + c * 4];
    __syncthreads();

    int cn = min(cnt[n], CAP);
    int base = n * CAP;
    int j  = base + ((cn * q) >> 2);
    int j1 = base + ((cn * (q + 1)) >> 2);
    float A = 0.f;
    for (; j + 3 < j1; j += 4) {
        int n0 = nbq[j], n1 = nbq[j+1], n2 = nbq[j+2], n3 = nbq[j+3];
        uint4 b0 = binc[j], b1 = binc[j+1], b2 = binc[j+2], b3 = binc[j+3];
        float sv0, sv1, sv2, sv3;
        if (L0) {
            sv0 = We[(n0 & 3) * 32 + c];
            sv1 = We[(n1 & 3) * 32 + c];
            sv2 = We[(n2 & 3) * 32 + c];
            sv3 = We[(n3 & 3) * 32 + c];
        } else {
            sv0 = b2f(slq[(n0 >> 2) * 32 + c]);
            sv1 = b2f(slq[(n1 >> 2) * 32 + c]);
            sv2 = b2f(slq[(n2 >> 2) * 32 + c]);
            sv3 = b2f(slq[(n3 >> 2) * 32 + c]);
        }
        A += dot8q(b0, wr) * sv0 + dot8q(b1, wr) * sv1
           + dot8q(b2, wr) * sv2 + dot8q(b3, wr) * sv3;
    }
    for (; j < j1; ++j) {
        int n0 = nbq[j];
        uint4 b0 = binc[j];
        float sv0 = L0 ? We[(n0 & 3) * 32 + c] : b2f(slq[(n0 >> 2) * 32 + c]);
        A += dot8q(b0, wr) * sv0;
    }
    Ash[al][q][c] = A;
    __syncthreads();
    if (q == 0) {
        float acc = 0.f;
#pragma unroll 8
        for (int cc = 0; cc < 32; cc++) {
            float Av = Ash[al][0][cc] + Ash[al][1][cc] + Ash[al][2][cc] + Ash[al][3][cc];
            acc += Av * wmix[cc * 32 + c];
        }
        float base_s = L0 ? We[at[n] * 32 + c] : b2f(slq[n * 32 + c]);
        soq[n * 32 + c] = f2b(base_s + acc);
    }
}

// ---------------- layer 2 fused: energy partial + barS2 + barA1(bf16); 2 atoms/block, 4 groups/atom ----------------
__global__ __launch_bounds__(256, 8) void k_L2E(
    const unsigned short* __restrict__ s2q,
    const int* __restrict__ cnt, const int* __restrict__ nbq, const uint4* __restrict__ binc,
    const float* __restrict__ Wrad2, const float* __restrict__ Wmix1,
    const float* __restrict__ w_out, const float* __restrict__ g2,
    float* __restrict__ barS2, unsigned short* __restrict__ ba1q, float* __restrict__ epart)
{
    __shared__ float wmixT[1056];   // Wmix1 transposed, stride 33
    __shared__ float Ash[2][4][32];
    __shared__ float Ssh[2][4][32];
    __shared__ float Bsh[2][32];
    int t = threadIdx.x;
    for (int i = t; i < 1024; i += 256) wmixT[(i & 31) * 33 + (i >> 5)] = Wmix1[i];
    int g = t >> 5, c = t & 31;
    int al = g >> 2, q = g & 3;
    int n = blockIdx.x * 2 + al;
    float wr[8];
#pragma unroll
    for (int bb = 0; bb < 8; bb++) wr[bb] = Wrad2[bb * 128 + c * 4];
    __syncthreads();

    int cn = min(cnt[n], CAP);
    int base = n * CAP;
    int j  = base + ((cn * q) >> 2);
    int j1 = base + ((cn * (q + 1)) >> 2);
    float A = 0.f, S = 0.f;
    for (; j + 3 < j1; j += 4) {
        int n0 = nbq[j], n1 = nbq[j+1], n2 = nbq[j+2], n3 = nbq[j+3];
        uint4 b0 = binc[j], b1 = binc[j+1], b2 = binc[j+2], b3 = binc[j+3];
        float r0 = dot8q(b0, wr), r1 = dot8q(b1, wr), r2 = dot8q(b2, wr), r3 = dot8q(b3, wr);
        A += r0 * b2f(s2q[(n0 >> 2) * 32 + c]) + r1 * b2f(s2q[(n1 >> 2) * 32 + c])
           + r2 * b2f(s2q[(n2 >> 2) * 32 + c]) + r3 * b2f(s2q[(n3 >> 2) * 32 + c]);
        S += r0 + r1 + r2 + r3;
    }
    for (; j < j1; ++j) {
        int n0 = nbq[j];
        float r0 = dot8q(binc[j], wr);
        A += r0 * b2f(s2q[(n0 >> 2) * 32 + c]);
        S += r0;
    }
    Ash[al][q][c] = A;
    Ssh[al][q][c] = S;
    __syncthreads();
    if (q == 0) {
        float At = Ash[al][0][c] + Ash[al][1][c] + Ash[al][2][c] + Ash[al][3][c];
        float St = Ssh[al][0][c] + Ssh[al][1][c] + Ssh[al][2][c] + Ssh[al][3][c];
        float woc = w_out[c], g2c = g2[c];
        float s2n = b2f(s2q[n * 32 + c]);
        float te = s2n * woc + At * g2c;
#pragma unroll
        for (int o = 1; o <= 16; o <<= 1) te += __shfl_xor(te, o, 32);
        if (c == 0) epart[n] = te;
        float bs2 = woc + g2c * St;
        barS2[n * 32 + c] = bs2;
        Bsh[al][c] = bs2;                 // same 32-lane group reads below (wave-internal order)
        float acc = 0.f;
#pragma unroll 8
        for (int d = 0; d < 32; d++) acc += Bsh[al][d] * wmixT[d * 33 + c];
        ba1q[n * 32 + c] = f2b(acc);
    }
}

// ---------------- backward l=1 fused: barS1 -> barA0 -> pk; 2 atoms/block, 4 groups/atom ----------------
// pk layout: x = s1 | s2<<16 ; y = ba0 | ba1<<16
__global__ __launch_bounds__(256, 8) void k_B1F(
    const unsigned short* __restrict__ ba1q, const float* __restrict__ barS2,
    const unsigned short* __restrict__ s1q, const unsigned short* __restrict__ s2q,
    const int* __restrict__ cnt, const int* __restrict__ nbq, const uint4* __restrict__ binc,
    const float* __restrict__ Wrad1, const float* __restrict__ Wmix0,
    uint2* __restrict__ pk)
{
    __shared__ float wmixT[1056];   // Wmix0 transposed, stride 33
    __shared__ float Ash[2][4][32];
    __shared__ float Bsh[2][32];
    int t = threadIdx.x;
    for (int i = t; i < 1024; i += 256) wmixT[(i & 31) * 33 + (i >> 5)] = Wmix0[i];
    int g = t >> 5, c = t & 31;
    int al = g >> 2, q = g & 3;
    int n = blockIdx.x * 2 + al;
    float wr[8];
#pragma unroll
    for (int bb = 0; bb < 8; bb++) wr[bb] = Wrad1[bb * 128 + c * 4];
    __syncthreads();

    int cn = min(cnt[n], CAP);
    int base = n * CAP;
    int j  = base + ((cn * q) >> 2);
    int j1 = base + ((cn * (q + 1)) >> 2);
    float A = 0.f;
    for (; j + 3 < j1; j += 4) {
        int n0 = nbq[j], n1 = nbq[j+1], n2 = nbq[j+2], n3 = nbq[j+3];
        uint4 b0 = binc[j], b1 = binc[j+1], b2 = binc[j+2], b3 = binc[j+3];
        A += dot8q(b0, wr) * b2f(ba1q[(n0 >> 2) * 32 + c])
           + dot8q(b1, wr) * b2f(ba1q[(n1 >> 2) * 32 + c])
           + dot8q(b2, wr) * b2f(ba1q[(n2 >> 2) * 32 + c])
           + dot8q(b3, wr) * b2f(ba1q[(n3 >> 2) * 32 + c]);
    }
    for (; j < j1; ++j) {
        int n0 = nbq[j];
        A += dot8q(binc[j], wr) * b2f(ba1q[(n0 >> 2) * 32 + c]);
    }
    Ash[al][q][c] = A;
    __syncthreads();
    if (q == 0) {
        float At = Ash[al][0][c] + Ash[al][1][c] + Ash[al][2][c] + Ash[al][3][c];
        int n32c = n * 32 + c;
        float bs1 = barS2[n32c] + At;
        Bsh[al][c] = bs1;
        float acc = 0.f;
#pragma unroll 8
        for (int d = 0; d < 32; d++) acc += Bsh[al][d] * wmixT[d * 33 + c];
        uint2 v;
        v.x = (unsigned)s1q[n32c] | ((unsigned)s2q[n32c] << 16);
        v.y = (unsigned)f2b(acc)  | ((unsigned)ba1q[n32c] << 16);
        pk[n32c] = v;
    }
}

// ---------------- energy reduction: 2048 per frame -> out[f] ----------------
__global__ __launch_bounds__(256) void k_ered(const float* __restrict__ epart, float* __restrict__ out)
{
    __shared__ float sm[256];
    int f = blockIdx.x, t = threadIdx.x;
    float a = 0.f;
    for (int i = t; i < N_AT; i += 256) a += epart[f * N_AT + i];
    sm[t] = a;
    __syncthreads();
    for (int s = 128; s; s >>= 1) {
        if (t < s) sm[t] += sm[t + s];
        __syncthreads();
    }
    if (t == 0) out[f] = sm[0];
}

// ---------------- forces, EDGE-PARALLEL: one 32-lane group per edge; uint2 rows + LDS s0 ----------------
#define EPG 8   // edges per 32-lane group
__global__ __launch_bounds__(256, 8) void k_force_e(
    const uint2* __restrict__ pk, const float* __restrict__ g2,
    const uint4* __restrict__ dbq, const float4* __restrict__ unit,
    const int* __restrict__ eidx, const int* __restrict__ at,
    const float* __restrict__ W_embed, const float* __restrict__ W_rad,
    float* __restrict__ out)
{
    __shared__ float We[128];
    int t = threadIdx.x;
    if (t < 128) We[t] = W_embed[t];
    int g = t >> 5;             // group 0..7 in block
    int c = t & 31;
    float wr0[8], wr1[8], wr2[8];
#pragma unroll
    for (int bb = 0; bb < 8; bb++) {
        wr0[bb] = W_rad[0 * 1024 + bb * 128 + c * 4];
        wr1[bb] = W_rad[1 * 1024 + bb * 128 + c * 4];
        wr2[bb] = W_rad[2 * 1024 + bb * 128 + c * 4];
    }
    float g2c = g2[c];
    __syncthreads();

    int kbase = (blockIdx.x * 8 + g) * EPG;
#pragma unroll 2
    for (int kk = 0; kk < EPG; ++kk) {
        int k = kbase + kk;
        int f = k >> 15;
        int e = k & (E_EDGE - 1);
        int a = eidx[f * 2 * E_EDGE + e] + f * N_AT;
        int b = eidx[f * 2 * E_EDGE + E_EDGE + e] + f * N_AT;
        uint4 d  = dbq[k];
        uint2 qa = pk[a * 32 + c];
        uint2 qb = pk[b * 32 + c];
        float s0a = We[at[a] * 32 + c];
        float s0b = We[at[b] * 32 + c];
        float dR0 = dot8q(d, wr0), dR1 = dot8q(d, wr1), dR2 = dot8q(d, wr2);
        float tc = dR0 * (blo(qa.y) * s0b + blo(qb.y) * s0a)
                 + dR1 * (bhi(qa.y) * blo(qb.x) + bhi(qb.y) * blo(qa.x))
                 + dR2 * g2c * (bhi(qa.x) + bhi(qb.x));
#pragma unroll
        for (int o = 1; o <= 16; o <<= 1) tc += __shfl_xor(tc, o, 32);
        float4 uv = unit[k];
        if (c < 3) {
            float uc = (c == 0) ? uv.x : (c == 1) ? uv.y : uv.z;
            atomicAdd(&out[8 + a * 3 + c], tc * uc);
        } else if (c < 6) {
            int d3 = c - 3;
            float uc = (d3 == 0) ? uv.x : (d3 == 1) ? uv.y : uv.z;
            atomicAdd(&out[8 + b * 3 + d3], -tc * uc);
        }
    }
}

extern "C" void kernel_launch(void* const* d_in, const int* in_sizes, int n_in,
                              void* d_out, int out_size, void* d_ws, size_t ws_size,
                              hipStream_t stream)
{
    const float* pos     = (const float*)d_in[0];
    const int*   eidx    = (const int*)  d_in[1];
    const float* cell    = (const float*)d_in[2];
    const int*   at      = (const int*)  d_in[3];
    const float* W_embed = (const float*)d_in[4];
    const float* W_rad   = (const float*)d_in[5];
    const float* W_mix   = (const float*)d_in[6];
    const float* w_out   = (const float*)d_in[7];
    const int*   co      = (const int*)  d_in[8];

    char* p = (char*)d_ws;
    auto carve = [&](size_t bytes) -> char* {
        char* r = p;
        p += (bytes + 255) & ~(size_t)255;
        return r;
    };
    uint4*          dbq    = (uint4*)          carve((size_t)FE * 16);
    float4*         unit   = (float4*)         carve((size_t)FE * 16);
    unsigned short* s1q    = (unsigned short*) carve((size_t)FN * 32 * 2);
    unsigned short* s2q    = (unsigned short*) carve((size_t)FN * 32 * 2);
    unsigned short* ba1q   = (unsigned short*) carve((size_t)FN * 32 * 2);
    float*          barS2  = (float*)          carve((size_t)FN * 32 * 4);
    uint2*          pk     = (uint2*)          carve((size_t)FN * 32 * 8);
    float*          g2     = (float*)          carve(32 * 4);
    float*          epart  = (float*)          carve((size_t)FN * 4);
    int*            cnt    = (int*)            carve((size_t)FN * 4);
    int*            nbq    = (int*)            carve((size_t)FN * CAP * 4);
    uint4*          binc   = (uint4*)          carve((size_t)FN * CAP * 16);

    hipMemsetAsync(cnt, 0, (size_t)FN * 4, stream);
    hipMemsetAsync(d_out, 0, (size_t)(8 + FN * 3) * 4, stream);  // energy + force accumulators

    k_edges<<<FE / 256, 256, 0, stream>>>(pos, eidx, cell, co, at, dbq, unit, cnt, nbq, binc);
    k_g2<<<1, 32, 0, stream>>>(w_out, W_mix + 2 * 1024, g2);

    // forward
    k_L<true><<<FN / 2, 256, 0, stream>>>(nullptr, W_embed, s1q, cnt, nbq, binc,
                                          W_rad + 0 * 1024, W_mix + 0 * 1024, at);
    k_L<false><<<FN / 2, 256, 0, stream>>>(s1q, W_embed, s2q, cnt, nbq, binc,
                                           W_rad + 1 * 1024, W_mix + 1 * 1024, at);
    // layer 2 + energy partials + barS2 + barA1
    k_L2E<<<FN / 2, 256, 0, stream>>>(s2q, cnt, nbq, binc, W_rad + 2 * 1024,
                                      W_mix + 1 * 1024, w_out, g2, barS2, ba1q, epart);
    // backward l=1 + barA0 + pack
    k_B1F<<<FN / 2, 256, 0, stream>>>(ba1q, barS2, s1q, s2q, cnt, nbq, binc,
                                      W_rad + 1 * 1024, W_mix + 0 * 1024, pk);
    // energy reduce
    k_ered<<<F_NUM, 256, 0, stream>>>(epart, (float*)d_out);
    // forces (edge-parallel, atomic accumulation)
    k_force_e<<<FE / (8 * EPG), 256, 0, stream>>>(pk, g2, dbq, unit, eidx, at, W_embed, W_rad, (float*)d_out);
}